// Round 5
// baseline (102.200 us; speedup 1.0000x reference)
//
#include <hip/hip_runtime.h>

// INRF fused:  out[b,ij,c] = sum_pq [ M2[ij,pq]*x[b,pq,c] - W2[ij,pq]*relu(x[b,pq,c] - S[b,pq,ij,c]) ]
//   S[b,pq,ij,f] = sum_k patch(x)[b,pq,k] * G[ij,k,f]   (3x3 SAME conv, K=144->pad 160)
//
// Round-5 = round-4 resubmitted (round-4 bench died to container infra, no data).
//   Theory under test: round-3's ~45us inrf_main was (a) the __launch_bounds__(512,2)
//   128-reg unified VGPR+AGPR cap forcing Bf/Af demotion (round-2 showed the
//   catastrophic version), (b) M/Wp epilogue global loads sitting unprefetched after
//   the MFMAs. Fixes:
//   - __launch_bounds__(512,1): ~256-reg budget, 1 block/CU (48KB LDS, 8 waves).
//   - one-tile-ahead M/Wp prefetch into statically-indexed mw[2] regs (parity ct&1).
//   - 256 blocks x 32 tiles (8 phases): exactly 1 block/CU, half the prologue/atomics.
//   Floor: 5120 MFMA/CU x 4.85cyc = 10.3us; VALU 3.8us, LDS 7.7us on separate pipes.

typedef __attribute__((ext_vector_type(8))) short bf16x8;
typedef __attribute__((ext_vector_type(4))) float f32x4;

__device__ inline unsigned short f2bf(float x) {
    unsigned u = __float_as_uint(x);
    u += 0x7FFFu + ((u >> 16) & 1u);          // round-to-nearest-even
    return (unsigned short)(u >> 16);
}
__device__ inline unsigned pack2(float a, float b) {
    return (unsigned)f2bf(a) | ((unsigned)f2bf(b) << 16);
}

__device__ inline void gld_lds16(const void* g, void* l) {
    __builtin_amdgcn_global_load_lds((const __attribute__((address_space(1))) void*)g,
                                     (__attribute__((address_space(3))) void*)l, 16, 0, 0);
}

// ---------------- Phase 1: A (im2col bf16 frags) + Xf (C-frag x) + Gf (bf16 B-frags) ----
// unit u = tid>>12:
//   u in [0,18): A tap = u>>1, h = u&1 -> uint4 at (tile, kk=tap>>1, quad=(tap&1)*2+h, m)
//   u == 18,19 : A zero-pad kk=4, quads 2,3
//   u in [20,24): Xf C-frag gather, one float4 per (tile, lane)
//   u in [24,28): zero out (16384 float4)
//   u in [28,108): Gf pack: one uint4 per (ij, kk, lane)
__global__ __launch_bounds__(256) void build_pre(const float* __restrict__ inp,
                                                 const float* __restrict__ G,
                                                 uint4* __restrict__ A,
                                                 float4* __restrict__ Xf,
                                                 uint4* __restrict__ Gf,
                                                 float4* __restrict__ outz) {
    const int tid = blockIdx.x * 256 + threadIdx.x;
    const int u = tid >> 12;
    if (u >= 28) {                            // G-pack: lane holds G[k=kk*32+quad*8+j][col]
        const int gidx = tid - 114688;        // 0..327679
        const int ijkk = gidx >> 6, l = gidx & 63;
        const int ij = ijkk / 5, kk = ijkk - ij * 5;
        const int quad = l >> 4, col = l & 15;
        const float* Gg = G + ij * 2304;
        float v[8];
#pragma unroll
        for (int j = 0; j < 8; ++j) {
            const int k = kk * 32 + quad * 8 + j;
            v[j] = (k < 144) ? Gg[k * 16 + col] : 0.f;
        }
        uint4 o;
        o.x = pack2(v[0], v[1]); o.y = pack2(v[2], v[3]);
        o.z = pack2(v[4], v[5]); o.w = pack2(v[6], v[7]);
        Gf[ij * 320 + kk * 64 + l] = o;
        return;
    }
    if (u >= 24) {
        outz[tid - 98304] = (float4){0.f, 0.f, 0.f, 0.f};
        return;
    }
    if (u >= 20) {
        const int idx = tid - 81920;          // 0..16383
        const int tile = idx >> 6, ll = idx & 63;
        const int rowb = tile * 16 + (ll >> 4) * 4;
        const int col = ll & 15;
        float4 v;
        v.x = inp[(rowb + 0) * 16 + col];
        v.y = inp[(rowb + 1) * 16 + col];
        v.z = inp[(rowb + 2) * 16 + col];
        v.w = inp[(rowb + 3) * 16 + col];
        Xf[idx] = v;
        return;
    }
    const int row = tid & 4095;
    const int tile = row >> 4, m = row & 15;
    if (u >= 18) {                            // zero-pad k=144..159 (kk=4, quads 2,3)
        const uint4 z = {0, 0, 0, 0};
        A[(tile * 5 + 4) * 64 + (u - 16) * 16 + m] = z;
        return;
    }
    const int tap = u >> 1, h = u & 1;
    const int dh = tap / 3, dw = tap - dh * 3;
    const int b = row >> 10, pq = row & 1023;
    const int p = pq >> 5, q = pq & 31;
    const int pp = p + dh - 1, qq = q + dw - 1;
    const int kk = tap >> 1, quad = (tap & 1) * 2 + h;
    uint4 o = {0, 0, 0, 0};
    if (((unsigned)pp < 32u) && ((unsigned)qq < 32u)) {
        const float4* s = (const float4*)(inp + b * 16384 + (pp * 32 + qq) * 16 + 8 * h);
        const float4 f0 = s[0], f1 = s[1];
        o.x = pack2(f0.x, f0.y); o.y = pack2(f0.z, f0.w);
        o.z = pack2(f1.x, f1.y); o.w = pack2(f1.z, f1.w);
    }
    A[(tile * 5 + kk) * 64 + quad * 16 + m] = o;
}

// ---------------- Phase 2: 256 blocks x 512 thr; 32 ij/block (4/wave), 32 tiles/block ---
__global__ __launch_bounds__(512, 1) void inrf_main(
    const float* __restrict__ M,     // (1024 ij, 1024 pq)
    const float* __restrict__ Wp,    // (1024 ij, 1024 pq)
    const uint4* __restrict__ Gf,    // bf16 B-frags: [ij*320 + kk*64 + lane]
    const uint4* __restrict__ Aw,    // swizzled bf16 patches, frag (tile,kk) at [..]*64+l
    const float4* __restrict__ Xf,   // x in C-frag layout
    float* __restrict__ out)         // (4,1024,16), pre-zeroed
{
    const int bid = blockIdx.x;
    const int ijblk = bid & 31;       // 32 ij-groups of 32 -> bid%8 = ijblk%8 (XCD co-loc)
    const int tgrp  = bid >> 5;       // 8 tile-groups of 32 tiles
    const int tile0 = tgrp * 32;
    const int bb    = tgrp >> 1;      // batch (32-tile groups never cross batches)

    const int t = threadIdx.x, l = t & 63, w = t >> 6;   // 8 waves
    const int quad = l >> 4;

    __shared__ __align__(16) uint4  Ab[2][4][5][64];   // 2 x (4 tiles x 5 kk) frags (40KB)
    __shared__ __align__(16) float4 Xb[2][4][64];      // 2 x (4 tiles) x-frags (8KB)

    // chunk staging: 24 wave-issues (20 A + 4 Xf), 3 per wave; dest wave-uniform + l*16B
    auto stage = [&](int buf, int ct0) {
#pragma unroll
        for (int r = 0; r < 3; ++r) {
            const int s = w * 3 + r;
            if (s < 20) {
                const int ct = s / 5, kk = s - ct * 5;
                gld_lds16(&Aw[((ct0 + ct) * 5 + kk) * 64 + l], &Ab[buf][ct][kk][0]);
            } else {
                const int ct = s - 20;
                gld_lds16(&Xf[(ct0 + ct) * 64 + l], &Xb[buf][ct][0]);
            }
        }
    };

    stage(0, tile0);                  // overlap chunk0 latency with Bf load

    // B fragments for this wave's 4 ij: 20 coalesced dwordx4 from Gf
    const int ij0 = ijblk * 32 + w * 4;
    bf16x8 Bf[4][5];
#pragma unroll
    for (int ij = 0; ij < 4; ++ij)
#pragma unroll
        for (int kk = 0; kk < 5; ++kk)
            Bf[ij][kk] = __builtin_bit_cast(bf16x8, Gf[(ij0 + ij) * 320 + kk * 64 + l]);

    // one-tile-ahead M/Wp prefetch regs; parity index is always compile-time (ct&1)
    float4 mwW[2][4], mwM[2][4];
    auto mwload = [&](int pbuf, int tgn) {
        const int pqb = (tgn & 63) * 16 + quad * 4;
#pragma unroll
        for (int jj = 0; jj < 4; ++jj) {
            mwW[pbuf][jj] = *(const float4*)&Wp[(ij0 + jj) * 1024 + pqb];
            mwM[pbuf][jj] = *(const float4*)&M [(ij0 + jj) * 1024 + pqb];
        }
    };

    mwload(0, tile0);                 // ctg = 0

    float accv[4] = {0.f, 0.f, 0.f, 0.f};

    asm volatile("s_waitcnt vmcnt(0)" ::: "memory");
    __syncthreads();

    int buf = 0;
#pragma unroll 1
    for (int ph = 0; ph < 8; ++ph) {
        if (ph < 7) stage(buf ^ 1, tile0 + (ph + 1) * 4);
#pragma unroll
        for (int ct = 0; ct < 4; ++ct) {
            const int ctg = ph * 4 + ct;
            // prefetch next tile's M/Wp (wraps harmlessly on the very last ct)
            mwload((ct + 1) & 1, tile0 + ((ctg + 1) & 31));

            uint4 Af[5];
#pragma unroll
            for (int kk = 0; kk < 5; ++kk) Af[kk] = Ab[buf][ct][kk][l];   // ds_read_b128
            const float4 vr = Xb[buf][ct][l];

            f32x4 C[4];
#pragma unroll
            for (int jj = 0; jj < 4; ++jj) C[jj] = (f32x4){0.f, 0.f, 0.f, 0.f};
#pragma unroll
            for (int kk = 0; kk < 5; ++kk) {
                const bf16x8 a = __builtin_bit_cast(bf16x8, Af[kk]);
#pragma unroll
                for (int jj = 0; jj < 4; ++jj)
                    C[jj] = __builtin_amdgcn_mfma_f32_16x16x32_bf16(
                                a, Bf[jj][kk], C[jj], 0, 0, 0);
            }

            // fused epilogue: acc += M2*x - W2*relu(x - S)
#pragma unroll
            for (int jj = 0; jj < 4; ++jj) {
                const float4 w2 = mwW[ct & 1][jj];
                const float4 m2 = mwM[ct & 1][jj];
                float a0 = accv[jj];
                a0 += m2.x * vr.x - w2.x * fmaxf(vr.x - C[jj][0], 0.f);
                a0 += m2.y * vr.y - w2.y * fmaxf(vr.y - C[jj][1], 0.f);
                a0 += m2.z * vr.z - w2.z * fmaxf(vr.z - C[jj][2], 0.f);
                a0 += m2.w * vr.w - w2.w * fmaxf(vr.w - C[jj][3], 0.f);
                accv[jj] = a0;
            }
        }
        asm volatile("s_waitcnt vmcnt(0)" ::: "memory");
        __syncthreads();
        buf ^= 1;
    }

    // quad-reduce -> 16 cols per ij; 2 tile-group blocks per batch combine via atomicAdd
#pragma unroll
    for (int jj = 0; jj < 4; ++jj) {
        float v = accv[jj];
        v += __shfl_xor(v, 16);
        v += __shfl_xor(v, 32);
        if (l < 16) atomicAdd(&out[bb * 16384 + (ij0 + jj) * 16 + l], v);
    }
}

extern "C" void kernel_launch(void* const* d_in, const int* in_sizes, int n_in,
                              void* d_out, int out_size, void* d_ws, size_t ws_size,
                              hipStream_t stream) {
    const float* inp = (const float*)d_in[0];   // 65536
    const float* M   = (const float*)d_in[1];   // 1048576
    const float* Wp  = (const float*)d_in[2];   // 1048576
    const float* G   = (const float*)d_in[3];   // 2359296
    float* out = (float*)d_out;

    uint4*  A  = (uint4*)d_ws;                                    // 81920*16B  = 1.31 MB
    float4* Xf = (float4*)((char*)d_ws + 1310720);                // 16384*16B  = 256 KB
    uint4*  Gf = (uint4*)((char*)d_ws + 1572864);                 // 327680*16B = 5.24 MB

    build_pre<<<dim3(1728), dim3(256), 0, stream>>>(inp, G, A, Xf, Gf, (float4*)out);
    inrf_main<<<dim3(256), dim3(512), 0, stream>>>(M, Wp, Gf, A, Xf, out);
}